// Round 1
// baseline (1072.699 us; speedup 1.0000x reference)
//
#include <hip/hip_runtime.h>
#include <hip/hip_bf16.h>

// Problem: B=128, T=2048, H=512
//   Wsum = Wa_w + Ua_w; bsum = Wa_b + Ua_b
//   pre[b,t,o]  = sum_h x[b,t,h] * Wsum[o,h] + bsum[o]
//   score[b,t]  = sum_o tanh(pre) * Va[o]        (+Va_b: softmax-invariant, dropped)
//   w = softmax_t(score);  context[b,h] = sum_t w[b,t] x[b,t,h]
// Outputs concat: context [B,H]=65536 floats, then weights [B,T]=262144 floats.

#define BB 128
#define TT 2048
#define HH 512

typedef __bf16 bf16_t;
typedef __bf16 bf16x4_t __attribute__((ext_vector_type(4)));
typedef __bf16 bf16x8_t __attribute__((ext_vector_type(8)));
typedef float f32x4_t __attribute__((ext_vector_type(4)));

__device__ __forceinline__ float tanh_fast(float x) {
    // tanh(x) = 1 - 2/(e^{2x}+1); exp overflow -> +1, underflow -> -1 (correct limits)
    float e = __expf(2.0f * x);
    return 1.0f - 2.0f * __builtin_amdgcn_rcpf(e + 1.0f);
}

// ---- kernel 0: Wsum (bf16) + bsum (fp32) prep -------------------------------
__global__ void prep_kernel(const float* __restrict__ wa, const float* __restrict__ ua,
                            const float* __restrict__ wab, const float* __restrict__ uab,
                            bf16_t* __restrict__ wsum, float* __restrict__ bsum) {
    int i = blockIdx.x * 256 + threadIdx.x;   // grid 1024*256 = 262144 = H*H
    wsum[i] = (bf16_t)(wa[i] + ua[i]);
    if (i < HH) bsum[i] = wab[i] + uab[i];
}

// ---- kernel 1: fused GEMM + tanh + Va-dot -> score (atomic partials) --------
// C[m,o] = sum_k x[m,k] * Wsum[o,k]; tile 128(M) x 128(N), BK=64, 4 waves 2x2,
// each wave 64x64 via 4x4 frags of mfma_f32_16x16x32_bf16.
__global__ __launch_bounds__(256) void gemm_score_kernel(
    const float* __restrict__ x, const bf16_t* __restrict__ wsum,
    const float* __restrict__ bsum, const float* __restrict__ va,
    float* __restrict__ score) {
    // +8 bf16 pad: row stride 144B -> fragment b128 reads are 2-way bank alias (free)
    __shared__ __align__(16) bf16_t As[128][72];
    __shared__ __align__(16) bf16_t Bs[128][72];

    const int tid  = threadIdx.x;
    const int lane = tid & 63;
    const int wave = tid >> 6;
    const int wm   = (wave >> 1) * 64;
    const int wn   = (wave & 1) * 64;
    const int quad = lane >> 4;
    const int lo   = lane & 15;
    const int m0   = blockIdx.x * 128;
    const int n0   = blockIdx.y * 128;

    f32x4_t acc[4][4];
#pragma unroll
    for (int mi = 0; mi < 4; ++mi)
#pragma unroll
        for (int ni = 0; ni < 4; ++ni)
            acc[mi][ni] = (f32x4_t){0.f, 0.f, 0.f, 0.f};

    const int ar = tid >> 4;         // A stage: 16 rows/pass, 16 float4 per row
    const int ac = (tid & 15) * 4;
    const int br = tid >> 3;         // B stage: 32 rows/pass, 8 bf16x8 per row
    const int bc = (tid & 7) * 8;

    for (int k0 = 0; k0 < HH; k0 += 64) {
        // stage A: fp32 -> bf16 in-register (global_load_lds can't convert)
#pragma unroll
        for (int p = 0; p < 8; ++p) {
            int row = p * 16 + ar;
            float4 v = *(const float4*)(x + (size_t)(m0 + row) * HH + k0 + ac);
            bf16x4_t bv;
            bv[0] = (bf16_t)v.x; bv[1] = (bf16_t)v.y;
            bv[2] = (bf16_t)v.z; bv[3] = (bf16_t)v.w;
            *(bf16x4_t*)&As[row][ac] = bv;
        }
        // stage B: already bf16
#pragma unroll
        for (int p = 0; p < 4; ++p) {
            int row = p * 32 + br;
            *(bf16x8_t*)&Bs[row][bc] =
                *(const bf16x8_t*)(wsum + (size_t)(n0 + row) * HH + k0 + bc);
        }
        __syncthreads();

#pragma unroll
        for (int kk = 0; kk < 64; kk += 32) {
            bf16x8_t a[4], b[4];
#pragma unroll
            for (int mi = 0; mi < 4; ++mi)
                a[mi] = *(const bf16x8_t*)&As[wm + mi * 16 + lo][kk + quad * 8];
#pragma unroll
            for (int ni = 0; ni < 4; ++ni)
                b[ni] = *(const bf16x8_t*)&Bs[wn + ni * 16 + lo][kk + quad * 8];
#pragma unroll
            for (int mi = 0; mi < 4; ++mi)
#pragma unroll
                for (int ni = 0; ni < 4; ++ni)
                    acc[mi][ni] = __builtin_amdgcn_mfma_f32_16x16x32_bf16(
                        a[mi], b[ni], acc[mi][ni], 0, 0, 0);
        }
        __syncthreads();
    }

    // epilogue: score partial = sum over this tile's o-range of tanh(pre+bsum)*va
    // C/D layout: col = lane&15 (+16*ni), row = quad*4 + reg (+16*mi)
    float bsr[4], var[4];
#pragma unroll
    for (int ni = 0; ni < 4; ++ni) {
        int o = n0 + wn + ni * 16 + lo;
        bsr[ni] = bsum[o];
        var[ni] = va[o];
    }
#pragma unroll
    for (int mi = 0; mi < 4; ++mi) {
#pragma unroll
        for (int r = 0; r < 4; ++r) {
            float s = 0.f;
#pragma unroll
            for (int ni = 0; ni < 4; ++ni)
                s += var[ni] * tanh_fast(acc[mi][ni][r] + bsr[ni]);
            // reduce across the 16 lanes (lo) sharing this row
            s += __shfl_xor(s, 1);
            s += __shfl_xor(s, 2);
            s += __shfl_xor(s, 4);
            s += __shfl_xor(s, 8);
            if (lo == 0)
                atomicAdd(&score[m0 + wm + mi * 16 + quad * 4 + r], s);
        }
    }
}

// ---- kernel 2: softmax over T per batch -------------------------------------
__global__ void softmax_kernel(const float* __restrict__ score, float* __restrict__ wout) {
    const int b = blockIdx.x;
    const int tid = threadIdx.x;
    const int lane = tid & 63;
    const int wave = tid >> 6;
    float s[8];
    float mx = -3.4e38f;
#pragma unroll
    for (int i = 0; i < 8; ++i) {
        s[i] = score[b * TT + i * 256 + tid];
        mx = fmaxf(mx, s[i]);
    }
#pragma unroll
    for (int off = 32; off; off >>= 1) mx = fmaxf(mx, __shfl_xor(mx, off));
    __shared__ float rmx[4], rsum[4];
    if (lane == 0) rmx[wave] = mx;
    __syncthreads();
    mx = fmaxf(fmaxf(rmx[0], rmx[1]), fmaxf(rmx[2], rmx[3]));
    float e[8];
    float sum = 0.f;
#pragma unroll
    for (int i = 0; i < 8; ++i) {
        e[i] = __expf(s[i] - mx);
        sum += e[i];
    }
#pragma unroll
    for (int off = 32; off; off >>= 1) sum += __shfl_xor(sum, off);
    if (lane == 0) rsum[wave] = sum;
    __syncthreads();
    sum = rsum[0] + rsum[1] + rsum[2] + rsum[3];
    float inv = 1.0f / sum;
#pragma unroll
    for (int i = 0; i < 8; ++i)
        wout[b * TT + i * 256 + tid] = e[i] * inv;
}

// ---- kernel 3: context partials over t-chunks -------------------------------
// grid (BB, 16); block 256; each thread owns 2 h columns (float2), 128 t per chunk
__global__ void context_partial_kernel(const float* __restrict__ x,
                                       const float* __restrict__ w,
                                       float* __restrict__ part) {
    const int b = blockIdx.x, tc = blockIdx.y, tid = threadIdx.x;
    __shared__ float lw[128];
    if (tid < 128) lw[tid] = w[b * TT + tc * 128 + tid];
    __syncthreads();
    const float* xp = x + ((size_t)b * TT + tc * 128) * HH + tid * 2;
    float ax = 0.f, ay = 0.f;
#pragma unroll 4
    for (int i = 0; i < 128; ++i) {
        float2 v = *(const float2*)(xp + (size_t)i * HH);
        float wv = lw[i];
        ax = fmaf(wv, v.x, ax);
        ay = fmaf(wv, v.y, ay);
    }
    float2 o;
    o.x = ax; o.y = ay;
    *(float2*)&part[((size_t)tc * BB + b) * HH + tid * 2] = o;
}

// ---- kernel 4: reduce partials -> context -----------------------------------
__global__ void context_reduce_kernel(const float* __restrict__ part, float* __restrict__ out) {
    int idx = blockIdx.x * 256 + threadIdx.x;   // < BB*HH = 65536
    float s = 0.f;
#pragma unroll
    for (int tc = 0; tc < 16; ++tc) s += part[tc * (BB * HH) + idx];
    out[idx] = s;
}

extern "C" void kernel_launch(void* const* d_in, const int* in_sizes, int n_in,
                              void* d_out, int out_size, void* d_ws, size_t ws_size,
                              hipStream_t stream) {
    const float* x   = (const float*)d_in[0];   // [B,T,H]
    const float* wa  = (const float*)d_in[1];   // [H,H]
    const float* wab = (const float*)d_in[2];   // [H]
    const float* ua  = (const float*)d_in[3];   // [H,H]
    const float* uab = (const float*)d_in[4];   // [H]
    const float* vaw = (const float*)d_in[5];   // [1,H]
    // d_in[6] = Va_b: softmax shift-invariant, unused

    float* ctx_out = (float*)d_out;             // [B,H]
    float* w_out   = (float*)d_out + BB * HH;   // [B,T]

    char* ws = (char*)d_ws;
    float*  score = (float*)ws;                                   // 1 MiB
    bf16_t* wsum  = (bf16_t*)(ws + (1 << 20));                    // 512 KiB
    float*  bsum  = (float*)(ws + (1 << 20) + HH * HH * 2);       // 2 KiB
    float*  part  = (float*)(ws + (1 << 20) + HH * HH * 2 + 4096);// 4 MiB

    hipMemsetAsync(score, 0, (size_t)BB * TT * sizeof(float), stream);
    prep_kernel<<<HH * HH / 256, 256, 0, stream>>>(wa, ua, wab, uab, wsum, bsum);
    gemm_score_kernel<<<dim3(BB * TT / 128, HH / 128), 256, 0, stream>>>(
        x, wsum, bsum, vaw, score);
    softmax_kernel<<<BB, 256, 0, stream>>>(score, w_out);
    context_partial_kernel<<<dim3(BB, 16), 256, 0, stream>>>(x, w_out, part);
    context_reduce_kernel<<<BB * HH / 256, 256, 0, stream>>>(part, ctx_out);
}